// Round 15
// baseline (541.047 us; speedup 1.0000x reference)
//
#include <hip/hip_runtime.h>
#include <hip/hip_bf16.h>

// Problem constants
#define BATCH 4
#define SEQ   2048
#define DM    1024
#define NH    16
#define DEPTH 64
#define ROWS  (BATCH*SEQ)   // 8192
#define NQKV  (3*DM)        // 3072
#define BH    (BATCH*NH)    // 64

typedef __attribute__((ext_vector_type(8))) short bf16x8;
typedef __attribute__((ext_vector_type(4))) float f32x4;
typedef __attribute__((ext_vector_type(16))) float f32x16;
typedef unsigned short u16;
typedef unsigned int   u32;

__device__ __forceinline__ u16 f2bf(float f) {
    union { float f; unsigned u; } v; v.f = f;
    unsigned r = v.u + 0x7fff + ((v.u >> 16) & 1);   // RNE
    return (u16)(r >> 16);
}

__device__ __forceinline__ u32 pk2bf(float a, float b) {
#if __has_builtin(__builtin_amdgcn_cvt_pk_bf16_f32)
    typedef __attribute__((ext_vector_type(2))) __bf16 v2bf;
    union { v2bf v; u32 u; } u_;
    u_.v = __builtin_amdgcn_cvt_pk_bf16_f32(a, b);
    return u_.u;
#else
    return (u32)f2bf(a) | ((u32)f2bf(b) << 16);
#endif
}

// permlane32_swap: x = lane<32 ? a : b[lane-32] ; y = lane<32 ? a[lane+32] : b
__device__ __forceinline__ void plswap(u32 a, u32 b, u32& x, u32& y) {
#if __has_builtin(__builtin_amdgcn_permlane32_swap)
    typedef __attribute__((ext_vector_type(2))) int i32x2;
    i32x2 r = __builtin_amdgcn_permlane32_swap((int)a, (int)b, false, false);
    x = (u32)r.x; y = (u32)r.y;
#else
    u32 as = (u32)__shfl_xor((int)a, 32);
    u32 bs = (u32)__shfl_xor((int)b, 32);
    int h = (threadIdx.x >> 5) & 1;
    x = h ? bs : a;
    y = h ? b : as;
#endif
}

// async global->LDS, 16B per lane. LDS dest must be wave-uniform base + lane*16.
__device__ __forceinline__ void g2l16(void* lds, const void* g) {
    __builtin_amdgcn_global_load_lds((const __attribute__((address_space(1))) void*)g,
                                     (__attribute__((address_space(3))) void*)lds, 16, 0, 0);
}

// read one 16B MFMA fragment from an unpadded [rows][64] tile with XOR-granule swizzle:
// logical granule gl (8 elems) of row r lives at physical granule gl ^ (r&7).
__device__ __forceinline__ bf16x8 frag8(const u16* tile, int row, int gl) {
    return *(const bf16x8*)(tile + row * 64 + ((gl ^ (row & 7)) * 8));
}

__device__ __forceinline__ f32x16 mfma32(bf16x8 a, bf16x8 b, f32x16 c) {
    return __builtin_amdgcn_mfma_f32_32x32x16_bf16(a, b, c, 0, 0, 0);
}

// ---------------- fused prep: x->bf16 + LDS-tiled weight transposes ----------------
// grid x: [0,2048) cvt_x chunks of 4096 ; [2048,2816) Wqkv transpose (kt,m,h) ; [2816,3072) Wo transpose
__global__ __launch_bounds__(256) void k_prep(const float* __restrict__ x,
                                              const float* __restrict__ Wq, const float* __restrict__ Wk,
                                              const float* __restrict__ Wv, const float* __restrict__ Wo,
                                              u16* __restrict__ xb, u16* __restrict__ BT, u16* __restrict__ WoT) {
    __shared__ u16 T[64][65];
    int tid = threadIdx.x;
    int bx = blockIdx.x;
    if (bx < 2048) {
        int i = bx * 4096 + tid * 4;
        for (int l = 0; l < 4; ++l) {
            float4 v = *(const float4*)(x + i + l * 1024);
            ushort4 o; o.x = f2bf(v.x); o.y = f2bf(v.y); o.z = f2bf(v.z); o.w = f2bf(v.w);
            *(ushort4*)(xb + i + l * 1024) = o;
        }
        return;
    }
    if (bx < 2816) {
        int q = bx - 2048;
        int kt = q & 15, mh = q >> 4, m = mh >> 4, h = mh & 15;
        const float* W = (m == 0) ? Wq : (m == 1) ? Wk : Wv;
        const float* src = W + ((size_t)h * 1024 + kt * 64) * 64;   // src[r][e], stride 64
        int e = tid & 63, r0 = tid >> 6;
        for (int i = 0; i < 16; ++i) { int r = i * 4 + r0; T[r][e] = f2bf(src[r * 64 + e]); }
        __syncthreads();
        int kk = tid & 63, e0 = tid >> 6;
        u16* dst = BT + ((size_t)m * 1024 + h * 64) * 1024 + kt * 64;  // [e-row][k-col]
        for (int i = 0; i < 16; ++i) { int ee = i * 4 + e0; dst[ee * 1024 + kk] = T[kk][ee]; }
        return;
    }
    {
        int q = bx - 2816;
        int kt = q & 15, nt = q >> 4;
        const float* src = Wo + (size_t)kt * 64 * 1024 + nt * 64;   // src[r][c], stride 1024
        int c = tid & 63, r0 = tid >> 6;
        for (int i = 0; i < 16; ++i) { int r = i * 4 + r0; T[r][c] = f2bf(src[r * 1024 + c]); }
        __syncthreads();
        int kk = tid & 63, e0 = tid >> 6;
        u16* dst = WoT + (size_t)nt * 64 * 1024 + kt * 64;
        for (int i = 0; i < 16; ++i) { int ee = i * 4 + e0; dst[ee * 1024 + kk] = T[kk][ee]; }
    }
}

// ---------------- merged QKV projection GEMMs: 256x128 tiles, 8 waves @ 64x64/wave, depth-2 vmcnt ----------------
// (round-14 version, unchanged -- best so far)
__global__ __launch_bounds__(512, 2) void k_gemm_qkv(const u16* __restrict__ xb, const u16* __restrict__ Wt,
                                                     const float* __restrict__ bq, const float* __restrict__ bk,
                                                     const float* __restrict__ bv,
                                                     u16* __restrict__ Q, u16* __restrict__ K, u16* __restrict__ VT) {
    __shared__ u16 Al[2][256 * 64];
    __shared__ u16 Bl[2][128 * 64];
    int tid = threadIdx.x;
    int wave = tid >> 6, lane = tid & 63, l31 = lane & 31, h2 = lane >> 5;
    int wr = wave >> 1, wc = wave & 1;           // 4 M-strips x 2 N-strips (64x64 each)

    // bijective XCD swizzle: 768 = 8 * 96
    int b = blockIdx.x;
    int wg = (b & 7) * 96 + (b >> 3);

    bool isvt = (wg >= 512);
    int row0, col0;
    const u16 *Am, *Bm;
    if (!isvt) {
        row0 = (wg >> 4) * 256; col0 = (wg & 15) * 128;   // 32 x 16 tiles
        Am = xb + (size_t)row0 * 1024;                    // rows = x rows
        Bm = Wt + (size_t)col0 * 1024;                    // rows = output cols (WqkvT)
    } else {
        int b2 = wg - 512;
        row0 = (b2 >> 6) * 256; col0 = (b2 & 63) * 128;   // 4 x 64 tiles
        Am = Wt + (size_t)(2048 + row0) * 1024;           // rows = Wv out-dims (h*64+e)
        Bm = xb + (size_t)col0 * 1024;                    // rows = x rows (output cols)
    }

    f32x16 acc[2][2] = {};                       // [mi][ni]

    int srA[4], sgsA[4], sdstA[4];
#pragma unroll
    for (int l = 0; l < 4; ++l) {
        int idx = tid + l * 512;
        srA[l] = idx >> 3; sgsA[l] = ((idx & 7) ^ (srA[l] & 7)) * 8; sdstA[l] = idx * 8;
    }
    int srB[2], sgsB[2], sdstB[2];
#pragma unroll
    for (int l = 0; l < 2; ++l) {
        int idx = tid + l * 512;
        srB[l] = idx >> 3; sgsB[l] = ((idx & 7) ^ (srB[l] & 7)) * 8; sdstB[l] = idx * 8;
    }

#define QKV_STAGE(bufi, k0) \
    { _Pragma("unroll") for (int l = 0; l < 4; ++l) \
        g2l16(&Al[bufi][sdstA[l]], Am + srA[l] * 1024 + (k0) + sgsA[l]); \
      _Pragma("unroll") for (int l = 0; l < 2; ++l) \
        g2l16(&Bl[bufi][sdstB[l]], Bm + srB[l] * 1024 + (k0) + sgsB[l]); }

#define QKV_COMPUTE(bufi) \
    { _Pragma("unroll") for (int kk = 0; kk < 4; ++kk) { \
        bf16x8 a0_ = frag8(Al[bufi], wr * 64 + l31,      2 * kk + h2); \
        bf16x8 a1_ = frag8(Al[bufi], wr * 64 + 32 + l31, 2 * kk + h2); \
        bf16x8 b0_ = frag8(Bl[bufi], wc * 64 + l31,      2 * kk + h2); \
        bf16x8 b1_ = frag8(Bl[bufi], wc * 64 + 32 + l31, 2 * kk + h2); \
        acc[0][0] = mfma32(a0_, b0_, acc[0][0]); \
        acc[0][1] = mfma32(a0_, b1_, acc[0][1]); \
        acc[1][0] = mfma32(a1_, b0_, acc[1][0]); \
        acc[1][1] = mfma32(a1_, b1_, acc[1][1]); } }

    QKV_STAGE(0, 0)
    QKV_STAGE(1, 64)

    for (int t = 0; t < 15; ++t) {
        int cur = t & 1;
        asm volatile("s_waitcnt vmcnt(6)" ::: "memory");   // stage(t) landed; stage(t+1) still flying
        __builtin_amdgcn_s_barrier();
        asm volatile("" ::: "memory");
        __builtin_amdgcn_s_setprio(1);
        QKV_COMPUTE(cur)
        __builtin_amdgcn_s_setprio(0);
        asm volatile("" ::: "memory");
        __builtin_amdgcn_s_barrier();                       // all waves done reading buf[cur]
        if (t < 14) QKV_STAGE(cur, (t + 2) * 64)
    }
    asm volatile("s_waitcnt vmcnt(0)" ::: "memory");
    __builtin_amdgcn_s_barrier();
    asm volatile("" ::: "memory");
    QKV_COMPUTE(1)
#undef QKV_STAGE
#undef QKV_COMPUTE

    if (!isvt) {
        const float QSCALE = 0.125f * 1.4426950408889634f;   // 1/sqrt(64) * log2(e)
        int m = (col0 >= 1024);                               // block-uniform: Q or K half
        const float* bias = m ? bk : bq;
        u16* dst0 = m ? K : Q;
#pragma unroll
        for (int ni = 0; ni < 2; ++ni) {
            int c = col0 + wc * 64 + ni * 32 + l31;
            int h = (c >> 6) & 15, e = c & 63;
            float bval = bias[h * 64 + e];
#pragma unroll
            for (int mi = 0; mi < 2; ++mi)
#pragma unroll
                for (int reg = 0; reg < 16; ++reg) {
                    int rowg = row0 + wr * 64 + mi * 32 + (reg & 3) + 8 * (reg >> 2) + 4 * h2;
                    int b_ = rowg >> 11, s = rowg & 2047;
                    int bh = b_ * 16 + h;
                    float v = acc[mi][ni][reg] + bval;
                    if (!m) v *= QSCALE;
                    dst0[((size_t)bh * 2048 + s) * 64 + e] = f2bf(v);
                }
        }
    } else {
#pragma unroll
        for (int ni = 0; ni < 2; ++ni) {
            int c = col0 + wc * 64 + ni * 32 + l31;           // xb row index
            int b_ = c >> 11, s = c & 2047;
#pragma unroll
            for (int mi = 0; mi < 2; ++mi)
#pragma unroll
                for (int reg = 0; reg < 16; ++reg) {
                    int ii = row0 + wr * 64 + mi * 32 + (reg & 3) + 8 * (reg >> 2) + 4 * h2;  // h*64+e
                    float v = acc[mi][ni][reg] + bv[ii];
                    VT[((size_t)b_ * 1024 + ii) * 2048 + s] = f2bf(v);
                }
        }
    }
}

// ---------------- flash attention: T15 pipeline, XCD-local heads, COMPILE-TIME slot unroll ----------------
// Round-10 body verbatim (sc[2] array, literal kt indexing -- no references, no lacc), but the loop
// is peeled (t=0) + 5 x 6-body unroll (t=1..30) + tail (t=31) + drain, so every Kl/Vl slot index is a
// compile-time literal: all frag8/stage LDS base addresses become hoistable constants (the VALU
// addressing overhead that held VALUBusy at 60%).
__global__ __launch_bounds__(256, 4) void k_attn(const u16* __restrict__ Q, const u16* __restrict__ K,
                                                 const u16* __restrict__ VT, u16* __restrict__ A2) {
    __shared__ u16 Kl[2][64 * 64];
    __shared__ u16 Vl[3][64 * 64];
    int tid = threadIdx.x;
    int wave = tid >> 6, lane = tid & 63, l31 = lane & 31, h = lane >> 5;
    int i = blockIdx.x;
    int bh = (i & 7) * 8 + ((i >> 3) & 7);   // 8 consecutive-XCD blocks share 8 heads
    int m0 = (i >> 6) * 128;
    const u16* Qb = Q + (size_t)bh * 2048 * 64;
    const u16* Kb = K + (size_t)bh * 2048 * 64;
    const u16* Vb = VT + (size_t)bh * 64 * 2048;

    // staging pointers: 2 rounds x 256 threads x 16B cover one 64x64 tile
    const u16* kpc[2]; const u16* vpc[2]; int dsti[2];
    for (int l = 0; l < 2; ++l) {
        int idx = tid + l * 256, r = idx >> 3, gs = ((idx & 7) ^ (r & 7)) * 8;
        dsti[l] = idx * 8;
        kpc[l] = Kb + r * 64 + gs;
        vpc[l] = Vb + r * 2048 + gs;
    }

    // Q fragments direct from global (one-time): row = m0 + wave*32 + l31
    bf16x8 qb[4];
    {
        const u16* q0 = Qb + (size_t)(m0 + wave * 32 + l31) * 64 + h * 8;
#pragma unroll
        for (int s = 0; s < 4; ++s) qb[s] = *(const bf16x8*)(q0 + s * 16);
    }

    // prologue: stage K/V tile 0 -> slot 0, full drain once; advance pointers to tile 1
    for (int l = 0; l < 2; ++l) { g2l16(&Kl[0][dsti[l]], kpc[l]); g2l16(&Vl[0][dsti[l]], vpc[l]); }
    asm volatile("s_waitcnt vmcnt(0)" ::: "memory");
    __builtin_amdgcn_s_barrier();
    asm volatile("" ::: "memory");
    kpc[0] += 4096; kpc[1] += 4096; vpc[0] += 64; vpc[1] += 64;

    f32x16 oacc[2] = {};             // [dt]
    float lsum = 0.f;
    bf16x8 pa[4] = {};               // P A-frag of tile t-1 (carried across iterations)

    // exp2 + lsum + pack sc -> pa: VERBATIM round-10 block (plain sc[2] array, literal kt)
#define ATT_EXP \
    { float sq = 0.f; \
      _Pragma("unroll") for (int kt = 0; kt < 2; ++kt) \
      _Pragma("unroll") for (int gp = 0; gp < 2; ++gp) { \
          float e00 = __builtin_amdgcn_exp2f(sc[kt][(2 * gp) * 4 + 0]); \
          float e01 = __builtin_amdgcn_exp2f(sc[kt][(2 * gp) * 4 + 1]); \
          float e02 = __builtin_amdgcn_exp2f(sc[kt][(2 * gp) * 4 + 2]); \
          float e03 = __builtin_amdgcn_exp2f(sc[kt][(2 * gp) * 4 + 3]); \
          float e10 = __builtin_amdgcn_exp2f(sc[kt][(2 * gp + 1) * 4 + 0]); \
          float e11 = __builtin_amdgcn_exp2f(sc[kt][(2 * gp + 1) * 4 + 1]); \
          float e12 = __builtin_amdgcn_exp2f(sc[kt][(2 * gp + 1) * 4 + 2]); \
          float e13 = __builtin_amdgcn_exp2f(sc[kt][(2 * gp + 1) * 4 + 3]); \
          sq += ((e00 + e01) + (e02 + e03)) + ((e10 + e11) + (e12 + e13)); \
          u32 ue = pk2bf(e00, e01), ve = pk2bf(e02, e03); \
          u32 uo = pk2bf(e10, e11), vo = pk2bf(e12, e13); \
          u32 w0, w1, w2, w3; \
          plswap(ue, uo, w0, w2); \
          plswap(ve, vo, w1, w3); \
          union { bf16x8 v; u32 w[4]; } pu; \
          pu.w[0] = w0; pu.w[1] = w1; pu.w[2] = w2; pu.w[3] = w3; \
          pa[2 * kt + gp] = pu.v; \
      } \
      lsum += sq; }

    // one pipeline body (compile-time slots): stage tile(t+1) -> Kl[KN]/Vl[VW]; QK(t) from Kl[KS];
    // PV(t-1) from Vl[VR]; exp(t); vmcnt(0)+barrier; bump pointers.
#define ATT_BODY(KS, KN, VW, VR) \
    { \
        g2l16(&Kl[KN][dsti[0]], kpc[0]); g2l16(&Vl[VW][dsti[0]], vpc[0]); \
        g2l16(&Kl[KN][dsti[1]], kpc[1]); g2l16(&Vl[VW][dsti[1]], vpc[1]); \
        f32x16 sc[2] = {}; \
        __builtin_amdgcn_s_setprio(1); \
        _Pragma("unroll") for (int s = 0; s < 4; ++s) { \
            bf16x8 kf0 = frag8(Kl[KS], l31,      2 * s + h); \
            bf16x8 kf1 = frag8(Kl[KS], 32 + l31, 2 * s + h); \
            sc[0] = mfma32(kf0, qb[s], sc[0]); \
            sc[1] = mfma32(kf1, qb[s], sc[1]); \
        } \
        _Pragma("unroll") for (int s = 0; s < 4; ++s) { \
            bf16x8 bv0 = frag8(Vl[VR], l31,      2 * s + h); \
            bf16x8 bv1 = frag8(Vl[VR], 32 + l31, 2 * s + h); \
            oacc[0] = mfma32(pa[s], bv0, oacc[0]); \
            oacc[1] = mfma32(pa[s], bv1, oacc[1]); \
        } \
        __builtin_amdgcn_s_setprio(0); \
        ATT_EXP \
        asm volatile("s_waitcnt vmcnt(0)" ::: "memory"); \
        __builtin_amdgcn_s_barrier(); \
        asm volatile("" ::: "memory"); \
        kpc[0] += 4096; kpc[1] += 4096; vpc[0] += 64; vpc[1] += 64; \
    }

    // ---- t = 0 (peeled: stage tile1 -> K[1]/V[1]; QK only; no PV) ----
    {
        g2l16(&Kl[1][dsti[0]], kpc[0]); g2l16(&Vl[1][dsti[0]], vpc[0]);
        g2l16(&Kl[1][dsti[1]], kpc[1]); g2l16(&Vl[1][dsti[1]], vpc[1]);
        f32x16 sc[2] = {};
        __builtin_amdgcn_s_setprio(1);
#pragma unroll
        for (int s = 0; s < 4; ++s) {
            bf16x8 kf0 = frag8(Kl[0], l31,      2 * s + h);
            bf16x8 kf1 = frag8(Kl[0], 32 + l31, 2 * s + h);
            sc[0] = mfma32(kf0, qb[s], sc[0]);
            sc[1] = mfma32(kf1, qb[s], sc[1]);
        }
        __builtin_amdgcn_s_setprio(0);
        ATT_EXP
        asm volatile("s_waitcnt vmcnt(0)" ::: "memory");
        __builtin_amdgcn_s_barrier();
        asm volatile("" ::: "memory");
        kpc[0] += 4096; kpc[1] += 4096; vpc[0] += 64; vpc[1] += 64;
    }

    // ---- t = 1..30: 5 x 6 bodies; t=1+6u+j: KS=t&1, KN=!KS, VW=(t+1)%3, VR=(t-1)%3 ----
    for (int u = 0; u < 5; ++u) {
        ATT_BODY(1, 0, 2, 0)   // j=0 (t%6==1)
        ATT_BODY(0, 1, 0, 1)   // j=1
        ATT_BODY(1, 0, 1, 2)   // j=2
        ATT_BODY(0, 1, 2, 0)   // j=3
        ATT_BODY(1, 0, 0, 1)   // j=4
        ATT_BODY(0, 1, 1, 2)   // j=5
    }

    // ---- t = 31 (tail: no stage, no barrier): QK from K[1]; PV(30) from V[30%3=0]; exp(31) ----
    {
        f32x16 sc[2] = {};
        __builtin_amdgcn_s_setprio(1);
#pragma unroll
        for (int s = 0; s < 4; ++s) {
            bf16x8 kf0 = frag8(Kl[1], l31,      2 * s + h);
            bf16x8 kf1 = frag8(Kl[1], 32 + l31, 2 * s + h);
            sc[0] = mfma32(kf0, qb[s], sc[0]);
            sc[1] = mfma32(kf1, qb[s], sc[1]);
        }
#pragma unroll
        for (int s = 0; s < 4; ++s) {
            bf16x8 bv0 = frag8(Vl[0], l31,      2 * s + h);
            bf16x8 bv1 = frag8(Vl[0], 32 + l31, 2 * s + h);
            oacc[0] = mfma32(pa[s], bv0, oacc[0]);
            oacc[1] = mfma32(pa[s], bv1, oacc[1]);
        }
        __builtin_amdgcn_s_setprio(0);
        ATT_EXP
    }

    // ---- drain: PV(31) from Vl[31%3 = 1] (staged at t=30) ----
#pragma unroll
    for (int s = 0; s < 4; ++s) {
        bf16x8 bv0 = frag8(Vl[1], l31,      2 * s + h);
        bf16x8 bv1 = frag8(Vl[1], 32 + l31, 2 * s + h);
        oacc[0] = mfma32(pa[s], bv0, oacc[0]);
        oacc[1] = mfma32(pa[s], bv1, oacc[1]);
    }
#undef ATT_BODY
#undef ATT_EXP

    // 1/l: combine h-halves in-register; redistribute to C-row layout via shuffles (no LDS)
    float linv_own;
    {
        float l2 = lsum + __shfl_xor(lsum, 32);   // lane q (both halves) holds l for query q
        linv_own = 1.0f / l2;
    }
    int b_ = bh >> 4, hh = bh & 15;
    for (int g = 0; g < 4; ++g) {
#pragma unroll
        for (int r = 0; r < 4; ++r) {
            float iv = __shfl(linv_own, 8 * g + 4 * h + r);
            int row = b_ * 2048 + m0 + wave * 32 + 8 * g + 4 * h + r;
            for (int dt = 0; dt < 2; ++dt)
                A2[row * 1024 + hh * 64 + dt * 32 + l31] = f2bf(oacc[dt][g * 4 + r] * iv);
        }
    }
}

// ---------------- output projection GEMM: 256x128 tiles, 8 waves @ 64x64/wave, depth-2 vmcnt ----------------
// (round-14 version, unchanged)
__global__ __launch_bounds__(512, 2) void k_gemm_out(const u16* __restrict__ A, const u16* __restrict__ BT,
                                                     const float* __restrict__ bo, float* __restrict__ out) {
    __shared__ u16 Al[2][256 * 64];
    __shared__ u16 Bl[2][128 * 64];
    int tid = threadIdx.x;
    int wave = tid >> 6, lane = tid & 63, l31 = lane & 31, h2 = lane >> 5;
    int wr = wave >> 1, wc = wave & 1;

    // bijective XCD swizzle: 256 = 8 * 32
    int b = blockIdx.x;
    int wg = (b & 7) * 32 + (b >> 3);
    int row0 = (wg >> 3) * 256, col0 = (wg & 7) * 128;

    const u16* Am = A  + (size_t)row0 * 1024;
    const u16* Bm = BT + (size_t)col0 * 1024;

    f32x16 acc[2][2] = {};

    int srA[4], sgsA[4], sdstA[4];
#pragma unroll
    for (int l = 0; l < 4; ++l) {
        int idx = tid + l * 512;
        srA[l] = idx >> 3; sgsA[l] = ((idx & 7) ^ (srA[l] & 7)) * 8; sdstA[l] = idx * 8;
    }
    int srB[2], sgsB[2], sdstB[2];
#pragma unroll
    for (int l = 0; l < 2; ++l) {
        int idx = tid + l * 512;
        srB[l] = idx >> 3; sgsB[l] = ((idx & 7) ^ (srB[l] & 7)) * 8; sdstB[l] = idx * 8;
    }

#define OUT_STAGE(bufi, k0) \
    { _Pragma("unroll") for (int l = 0; l < 4; ++l) \
        g2l16(&Al[bufi][sdstA[l]], Am + srA[l] * 1024 + (k0) + sgsA[l]); \
      _Pragma("unroll") for (int l = 0; l < 2; ++l) \
        g2l16(&Bl[bufi][sdstB[l]], Bm + srB[l] * 1024 + (k0) + sgsB[l]); }

#define OUT_COMPUTE(bufi) \
    { _Pragma("unroll") for (int kk = 0; kk < 4; ++kk) { \
        bf16x8 a0_ = frag8(Al[bufi], wr * 64 + l31,      2 * kk + h2); \
        bf16x8 a1_ = frag8(Al[bufi], wr * 64 + 32 + l31, 2 * kk + h2); \
        bf16x8 b0_ = frag8(Bl[bufi], wc * 64 + l31,      2 * kk + h2); \
        bf16x8 b1_ = frag8(Bl[bufi], wc * 64 + 32 + l31, 2 * kk + h2); \
        acc[0][0] = mfma32(a0_, b0_, acc[0][0]); \
        acc[0][1] = mfma32(a0_, b1_, acc[0][1]); \
        acc[1][0] = mfma32(a1_, b0_, acc[1][0]); \
        acc[1][1] = mfma32(a1_, b1_, acc[1][1]); } }

    OUT_STAGE(0, 0)
    OUT_STAGE(1, 64)

    for (int t = 0; t < 15; ++t) {
        int cur = t & 1;
        asm volatile("s_waitcnt vmcnt(6)" ::: "memory");
        __builtin_amdgcn_s_barrier();
        asm volatile("" ::: "memory");
        __builtin_amdgcn_s_setprio(1);
        OUT_COMPUTE(cur)
        __builtin_amdgcn_s_setprio(0);
        asm volatile("" ::: "memory");
        __builtin_amdgcn_s_barrier();
        if (t < 14) OUT_STAGE(cur, (t + 2) * 64)
    }
    asm volatile("s_waitcnt vmcnt(0)" ::: "memory");
    __builtin_amdgcn_s_barrier();
    asm volatile("" ::: "memory");
    OUT_COMPUTE(1)
#undef OUT_STAGE
#undef OUT_COMPUTE

#pragma unroll
    for (int ni = 0; ni < 2; ++ni) {
        int c = col0 + wc * 64 + ni * 32 + l31;
        float bias = bo[c];
#pragma unroll
        for (int mi = 0; mi < 2; ++mi)
#pragma unroll
            for (int reg = 0; reg < 16; ++reg) {
                int rowg = row0 + wr * 64 + mi * 32 + (reg & 3) + 8 * (reg >> 2) + 4 * h2;
                out[(size_t)rowg * 1024 + c] = acc[mi][ni][reg] + bias;
            }
    }
}

extern "C" void kernel_launch(void* const* d_in, const int* in_sizes, int n_in,
                              void* d_out, int out_size, void* d_ws, size_t ws_size,
                              hipStream_t stream) {
    const float* x  = (const float*)d_in[0];
    const float* Wq = (const float*)d_in[1];
    const float* bq = (const float*)d_in[2];
    const float* Wk = (const float*)d_in[3];
    const float* bk = (const float*)d_in[4];
    const float* Wv = (const float*)d_in[5];
    const float* bv = (const float*)d_in[6];
    const float* Wo = (const float*)d_in[7];
    const float* bo = (const float*)d_in[8];
    float* out = (float*)d_out;

    // Workspace layout (peak 72 MB). A2 aliases xb: xb is dead after k_gemm_qkv,
    // and A2 is first written by k_attn which runs strictly later on this stream.
    char* ws = (char*)d_ws;
    u16* xb    = (u16*)ws; ws += (size_t)ROWS * DM * 2;        // 16 MB
    u16* WqkvT = (u16*)ws; ws += (size_t)NQKV * DM * 2;        // 6 MB
    u16* WoT   = (u16*)ws; ws += (size_t)DM * DM * 2;          // 2 MB
    u16* Qb    = (u16*)ws; ws += (size_t)BH * SEQ * DEPTH * 2; // 16 MB
    u16* Kb    = (u16*)ws; ws += (size_t)BH * SEQ * DEPTH * 2; // 16 MB
    u16* VTb   = (u16*)ws; ws += (size_t)BH * SEQ * DEPTH * 2; // 16 MB
    u16* A2    = xb;                                           // aliased (16 MB)
    (void)ws_size;

    k_prep     <<<dim3(3072),   dim3(256), 0, stream>>>(x, Wq, Wk, Wv, Wo, xb, WqkvT, WoT);
    k_gemm_qkv <<<dim3(768),    dim3(512), 0, stream>>>(xb, WqkvT, bq, bk, bv, Qb, Kb, VTb);
    k_attn     <<<dim3(1024),   dim3(256), 0, stream>>>(Qb, Kb, VTb, A2);
    k_gemm_out <<<dim3(256),    dim3(512), 0, stream>>>(A2, WoT, bo, out);
}

// Round 16
// 276.631 us; speedup vs baseline: 1.9558x; 1.9558x over previous
//
#include <hip/hip_runtime.h>
#include <hip/hip_bf16.h>

// Problem constants
#define BATCH 4
#define SEQ   2048
#define DM    1024
#define NH    16
#define DEPTH 64
#define ROWS  (BATCH*SEQ)   // 8192
#define NQKV  (3*DM)        // 3072
#define BH    (BATCH*NH)    // 64

typedef __attribute__((ext_vector_type(8))) short bf16x8;
typedef __attribute__((ext_vector_type(4))) float f32x4;
typedef __attribute__((ext_vector_type(16))) float f32x16;
typedef unsigned short u16;
typedef unsigned int   u32;

__device__ __forceinline__ u16 f2bf(float f) {
    union { float f; unsigned u; } v; v.f = f;
    unsigned r = v.u + 0x7fff + ((v.u >> 16) & 1);   // RNE
    return (u16)(r >> 16);
}

__device__ __forceinline__ u32 pk2bf(float a, float b) {
#if __has_builtin(__builtin_amdgcn_cvt_pk_bf16_f32)
    typedef __attribute__((ext_vector_type(2))) __bf16 v2bf;
    union { v2bf v; u32 u; } u_;
    u_.v = __builtin_amdgcn_cvt_pk_bf16_f32(a, b);
    return u_.u;
#else
    return (u32)f2bf(a) | ((u32)f2bf(b) << 16);
#endif
}

// permlane32_swap: x = lane<32 ? a : b[lane-32] ; y = lane<32 ? a[lane+32] : b
__device__ __forceinline__ void plswap(u32 a, u32 b, u32& x, u32& y) {
#if __has_builtin(__builtin_amdgcn_permlane32_swap)
    typedef __attribute__((ext_vector_type(2))) int i32x2;
    i32x2 r = __builtin_amdgcn_permlane32_swap((int)a, (int)b, false, false);
    x = (u32)r.x; y = (u32)r.y;
#else
    u32 as = (u32)__shfl_xor((int)a, 32);
    u32 bs = (u32)__shfl_xor((int)b, 32);
    int h = (threadIdx.x >> 5) & 1;
    x = h ? bs : a;
    y = h ? b : as;
#endif
}

// async global->LDS, 16B per lane. LDS dest must be wave-uniform base + lane*16.
__device__ __forceinline__ void g2l16(void* lds, const void* g) {
    __builtin_amdgcn_global_load_lds((const __attribute__((address_space(1))) void*)g,
                                     (__attribute__((address_space(3))) void*)lds, 16, 0, 0);
}

// read one 16B MFMA fragment from an unpadded [rows][64] tile with XOR-granule swizzle:
// logical granule gl (8 elems) of row r lives at physical granule gl ^ (r&7).
__device__ __forceinline__ bf16x8 frag8(const u16* tile, int row, int gl) {
    return *(const bf16x8*)(tile + row * 64 + ((gl ^ (row & 7)) * 8));
}

__device__ __forceinline__ f32x16 mfma32(bf16x8 a, bf16x8 b, f32x16 c) {
    return __builtin_amdgcn_mfma_f32_32x32x16_bf16(a, b, c, 0, 0, 0);
}

// ---------------- fused prep: x->bf16 + LDS-tiled weight transposes ----------------
// grid x: [0,2048) cvt_x chunks of 4096 ; [2048,2816) Wqkv transpose (kt,m,h) ; [2816,3072) Wo transpose
__global__ __launch_bounds__(256) void k_prep(const float* __restrict__ x,
                                              const float* __restrict__ Wq, const float* __restrict__ Wk,
                                              const float* __restrict__ Wv, const float* __restrict__ Wo,
                                              u16* __restrict__ xb, u16* __restrict__ BT, u16* __restrict__ WoT) {
    __shared__ u16 T[64][65];
    int tid = threadIdx.x;
    int bx = blockIdx.x;
    if (bx < 2048) {
        int i = bx * 4096 + tid * 4;
        for (int l = 0; l < 4; ++l) {
            float4 v = *(const float4*)(x + i + l * 1024);
            ushort4 o; o.x = f2bf(v.x); o.y = f2bf(v.y); o.z = f2bf(v.z); o.w = f2bf(v.w);
            *(ushort4*)(xb + i + l * 1024) = o;
        }
        return;
    }
    if (bx < 2816) {
        int q = bx - 2048;
        int kt = q & 15, mh = q >> 4, m = mh >> 4, h = mh & 15;
        const float* W = (m == 0) ? Wq : (m == 1) ? Wk : Wv;
        const float* src = W + ((size_t)h * 1024 + kt * 64) * 64;   // src[r][e], stride 64
        int e = tid & 63, r0 = tid >> 6;
        for (int i = 0; i < 16; ++i) { int r = i * 4 + r0; T[r][e] = f2bf(src[r * 64 + e]); }
        __syncthreads();
        int kk = tid & 63, e0 = tid >> 6;
        u16* dst = BT + ((size_t)m * 1024 + h * 64) * 1024 + kt * 64;  // [e-row][k-col]
        for (int i = 0; i < 16; ++i) { int ee = i * 4 + e0; dst[ee * 1024 + kk] = T[kk][ee]; }
        return;
    }
    {
        int q = bx - 2816;
        int kt = q & 15, nt = q >> 4;
        const float* src = Wo + (size_t)kt * 64 * 1024 + nt * 64;   // src[r][c], stride 1024
        int c = tid & 63, r0 = tid >> 6;
        for (int i = 0; i < 16; ++i) { int r = i * 4 + r0; T[r][c] = f2bf(src[r * 1024 + c]); }
        __syncthreads();
        int kk = tid & 63, e0 = tid >> 6;
        u16* dst = WoT + (size_t)nt * 64 * 1024 + kt * 64;
        for (int i = 0; i < 16; ++i) { int ee = i * 4 + e0; dst[ee * 1024 + kk] = T[kk][ee]; }
    }
}

// ---------------- merged QKV projection GEMMs: 256x128 tiles, 8 waves @ 64x64/wave, depth-2 vmcnt ----------------
// 768 blocks of 512 threads (8 waves, 4Mx2N; per-wave 64x64 via 32x32x16 MFMA).
// LDS = 96 KB (A 2x32KB + B 2x16KB) -> 1 block/CU; counted vmcnt(6) keeps 2 K-tiles in flight so
// the barrier never exposes full load latency. Per kk: 4 ds_read_b128 -> 4 MFMA (1:1).
__global__ __launch_bounds__(512, 2) void k_gemm_qkv(const u16* __restrict__ xb, const u16* __restrict__ Wt,
                                                     const float* __restrict__ bq, const float* __restrict__ bk,
                                                     const float* __restrict__ bv,
                                                     u16* __restrict__ Q, u16* __restrict__ K, u16* __restrict__ VT) {
    __shared__ u16 Al[2][256 * 64];
    __shared__ u16 Bl[2][128 * 64];
    int tid = threadIdx.x;
    int wave = tid >> 6, lane = tid & 63, l31 = lane & 31, h2 = lane >> 5;
    int wr = wave >> 1, wc = wave & 1;           // 4 M-strips x 2 N-strips (64x64 each)

    // bijective XCD swizzle: 768 = 8 * 96
    int b = blockIdx.x;
    int wg = (b & 7) * 96 + (b >> 3);

    bool isvt = (wg >= 512);
    int row0, col0;
    const u16 *Am, *Bm;
    if (!isvt) {
        row0 = (wg >> 4) * 256; col0 = (wg & 15) * 128;   // 32 x 16 tiles
        Am = xb + (size_t)row0 * 1024;                    // rows = x rows
        Bm = Wt + (size_t)col0 * 1024;                    // rows = output cols (WqkvT)
    } else {
        int b2 = wg - 512;
        row0 = (b2 >> 6) * 256; col0 = (b2 & 63) * 128;   // 4 x 64 tiles
        Am = Wt + (size_t)(2048 + row0) * 1024;           // rows = Wv out-dims (h*64+e)
        Bm = xb + (size_t)col0 * 1024;                    // rows = x rows (output cols)
    }

    f32x16 acc[2][2] = {};                       // [mi][ni]

    int srA[4], sgsA[4], sdstA[4];
#pragma unroll
    for (int l = 0; l < 4; ++l) {
        int idx = tid + l * 512;
        srA[l] = idx >> 3; sgsA[l] = ((idx & 7) ^ (srA[l] & 7)) * 8; sdstA[l] = idx * 8;
    }
    int srB[2], sgsB[2], sdstB[2];
#pragma unroll
    for (int l = 0; l < 2; ++l) {
        int idx = tid + l * 512;
        srB[l] = idx >> 3; sgsB[l] = ((idx & 7) ^ (srB[l] & 7)) * 8; sdstB[l] = idx * 8;
    }

#define QKV_STAGE(bufi, k0) \
    { _Pragma("unroll") for (int l = 0; l < 4; ++l) \
        g2l16(&Al[bufi][sdstA[l]], Am + srA[l] * 1024 + (k0) + sgsA[l]); \
      _Pragma("unroll") for (int l = 0; l < 2; ++l) \
        g2l16(&Bl[bufi][sdstB[l]], Bm + srB[l] * 1024 + (k0) + sgsB[l]); }

#define QKV_COMPUTE(bufi) \
    { _Pragma("unroll") for (int kk = 0; kk < 4; ++kk) { \
        bf16x8 a0_ = frag8(Al[bufi], wr * 64 + l31,      2 * kk + h2); \
        bf16x8 a1_ = frag8(Al[bufi], wr * 64 + 32 + l31, 2 * kk + h2); \
        bf16x8 b0_ = frag8(Bl[bufi], wc * 64 + l31,      2 * kk + h2); \
        bf16x8 b1_ = frag8(Bl[bufi], wc * 64 + 32 + l31, 2 * kk + h2); \
        acc[0][0] = mfma32(a0_, b0_, acc[0][0]); \
        acc[0][1] = mfma32(a0_, b1_, acc[0][1]); \
        acc[1][0] = mfma32(a1_, b0_, acc[1][0]); \
        acc[1][1] = mfma32(a1_, b1_, acc[1][1]); } }

    QKV_STAGE(0, 0)
    QKV_STAGE(1, 64)

    for (int t = 0; t < 15; ++t) {
        int cur = t & 1;
        asm volatile("s_waitcnt vmcnt(6)" ::: "memory");   // stage(t) landed; stage(t+1) still flying
        __builtin_amdgcn_s_barrier();
        asm volatile("" ::: "memory");
        __builtin_amdgcn_s_setprio(1);
        QKV_COMPUTE(cur)
        __builtin_amdgcn_s_setprio(0);
        asm volatile("" ::: "memory");
        __builtin_amdgcn_s_barrier();                       // all waves done reading buf[cur]
        if (t < 14) QKV_STAGE(cur, (t + 2) * 64)
    }
    asm volatile("s_waitcnt vmcnt(0)" ::: "memory");
    __builtin_amdgcn_s_barrier();
    asm volatile("" ::: "memory");
    QKV_COMPUTE(1)
#undef QKV_STAGE
#undef QKV_COMPUTE

    if (!isvt) {
        const float QSCALE = 0.125f * 1.4426950408889634f;   // 1/sqrt(64) * log2(e)
        int m = (col0 >= 1024);                               // block-uniform: Q or K half
        const float* bias = m ? bk : bq;
        u16* dst0 = m ? K : Q;
#pragma unroll
        for (int ni = 0; ni < 2; ++ni) {
            int c = col0 + wc * 64 + ni * 32 + l31;
            int h = (c >> 6) & 15, e = c & 63;
            float bval = bias[h * 64 + e];
#pragma unroll
            for (int mi = 0; mi < 2; ++mi)
#pragma unroll
                for (int reg = 0; reg < 16; ++reg) {
                    int rowg = row0 + wr * 64 + mi * 32 + (reg & 3) + 8 * (reg >> 2) + 4 * h2;
                    int b_ = rowg >> 11, s = rowg & 2047;
                    int bh = b_ * 16 + h;
                    float v = acc[mi][ni][reg] + bval;
                    if (!m) v *= QSCALE;
                    dst0[((size_t)bh * 2048 + s) * 64 + e] = f2bf(v);
                }
        }
    } else {
#pragma unroll
        for (int ni = 0; ni < 2; ++ni) {
            int c = col0 + wc * 64 + ni * 32 + l31;           // xb row index
            int b_ = c >> 11, s = c & 2047;
#pragma unroll
            for (int mi = 0; mi < 2; ++mi)
#pragma unroll
                for (int reg = 0; reg < 16; ++reg) {
                    int ii = row0 + wr * 64 + mi * 32 + (reg & 3) + 8 * (reg >> 2) + 4 * h2;  // h*64+e
                    float v = acc[mi][ni][reg] + bv[ii];
                    VT[((size_t)b_ * 1024 + ii) * 2048 + s] = f2bf(v);
                }
        }
    }
}

// ---------------- flash attention: T15 pipeline + XCD-local heads + single barrier/iter ----------------
// (round-10/14 structure verbatim -- known-good ~100 us; runtime slot indices keep registers in budget:
//  full unrolling spills (rounds 11 & 15), lacc-on-MFMA lengthens the critical MFMA chain (round 12))
__global__ __launch_bounds__(256, 4) void k_attn(const u16* __restrict__ Q, const u16* __restrict__ K,
                                                 const u16* __restrict__ VT, u16* __restrict__ A2) {
    __shared__ u16 Kl[2][64 * 64];
    __shared__ u16 Vl[3][64 * 64];
    int tid = threadIdx.x;
    int wave = tid >> 6, lane = tid & 63, l31 = lane & 31, h = lane >> 5;
    int i = blockIdx.x;
    int bh = (i & 7) * 8 + ((i >> 3) & 7);   // 8 consecutive-XCD blocks share 8 heads
    int m0 = (i >> 6) * 128;
    const u16* Qb = Q + (size_t)bh * 2048 * 64;
    const u16* Kb = K + (size_t)bh * 2048 * 64;
    const u16* Vb = VT + (size_t)bh * 64 * 2048;

    // staging pointers: 2 rounds x 256 threads x 16B cover one 64x64 tile
    const u16* kp[2]; const u16* vp[2]; int dsti[2];
    for (int l = 0; l < 2; ++l) {
        int idx = tid + l * 256, r = idx >> 3, gs = ((idx & 7) ^ (r & 7)) * 8;
        dsti[l] = idx * 8;
        kp[l] = Kb + r * 64 + gs;
        vp[l] = Vb + r * 2048 + gs;
    }

    // Q fragments direct from global (one-time): row = m0 + wave*32 + l31,
    // elements 16s + 8h .. +7 (B-operand: n=query=lane&31, k=16s+8h+i)
    bf16x8 qb[4];
    {
        const u16* q0 = Qb + (size_t)(m0 + wave * 32 + l31) * 64 + h * 8;
#pragma unroll
        for (int s = 0; s < 4; ++s) qb[s] = *(const bf16x8*)(q0 + s * 16);
    }

    // prologue: stage K/V tile 0 -> slot 0, full drain once
    for (int l = 0; l < 2; ++l) { g2l16(&Kl[0][dsti[l]], kp[l]); g2l16(&Vl[0][dsti[l]], vp[l]); }
    asm volatile("s_waitcnt vmcnt(0)" ::: "memory");
    __builtin_amdgcn_s_barrier();
    asm volatile("" ::: "memory");

    f32x16 oacc[2] = {};             // [dt]
    float lsum = 0.f;
    bf16x8 pa[4] = {};               // P A-frag of tile t-1 (carried across iterations)
    int vw = 1;                      // V write slot = (t+1)%3
    int vr = 2;                      // V read slot for PV(t-1) = (t-1)%3 (t=0: unused)

    for (int t = 0; t < 32; ++t) {
        int cur = t & 1, nxt = cur ^ 1;

        // stage K(t+1) and V(t+1) at the top -- full-body flight before the end barrier
        if (t < 31) {
            for (int l = 0; l < 2; ++l) {
                g2l16(&Kl[nxt][dsti[l]], kp[l] + (t + 1) * 4096);
                g2l16(&Vl[vw][dsti[l]], vp[l] + (t + 1) * 64);
            }
        }

        // MFMA burst: QK(t) + PV(t-1)  (sc[0], sc[1], oacc[0], oacc[1] = 4 indep chains)
        f32x16 sc[2] = {};           // [kt]
        __builtin_amdgcn_s_setprio(1);
#pragma unroll
        for (int s = 0; s < 4; ++s) {
            bf16x8 kf0 = frag8(Kl[cur], l31,      2 * s + h);
            bf16x8 kf1 = frag8(Kl[cur], 32 + l31, 2 * s + h);
            sc[0] = mfma32(kf0, qb[s], sc[0]);
            sc[1] = mfma32(kf1, qb[s], sc[1]);
        }
        if (t > 0) {
            const u16* vt_ = Vl[vr];
#pragma unroll
            for (int s = 0; s < 4; ++s) {
                bf16x8 bv0 = frag8(vt_, l31,      2 * s + h);
                bf16x8 bv1 = frag8(vt_, 32 + l31, 2 * s + h);
                oacc[0] = mfma32(pa[s], bv0, oacc[0]);
                oacc[1] = mfma32(pa[s], bv1, oacc[1]);
            }
        }
        __builtin_amdgcn_s_setprio(0);

        // exp2 + lsum + in-register P -> A-fragment (VALU, under K/V-load flight)
        float sq = 0.f;
#pragma unroll
        for (int kt = 0; kt < 2; ++kt)
#pragma unroll
            for (int gp = 0; gp < 2; ++gp) {
                float e00 = __builtin_amdgcn_exp2f(sc[kt][(2 * gp) * 4 + 0]);
                float e01 = __builtin_amdgcn_exp2f(sc[kt][(2 * gp) * 4 + 1]);
                float e02 = __builtin_amdgcn_exp2f(sc[kt][(2 * gp) * 4 + 2]);
                float e03 = __builtin_amdgcn_exp2f(sc[kt][(2 * gp) * 4 + 3]);
                float e10 = __builtin_amdgcn_exp2f(sc[kt][(2 * gp + 1) * 4 + 0]);
                float e11 = __builtin_amdgcn_exp2f(sc[kt][(2 * gp + 1) * 4 + 1]);
                float e12 = __builtin_amdgcn_exp2f(sc[kt][(2 * gp + 1) * 4 + 2]);
                float e13 = __builtin_amdgcn_exp2f(sc[kt][(2 * gp + 1) * 4 + 3]);
                sq += ((e00 + e01) + (e02 + e03)) + ((e10 + e11) + (e12 + e13));
                u32 ue = pk2bf(e00, e01), ve = pk2bf(e02, e03);
                u32 uo = pk2bf(e10, e11), vo = pk2bf(e12, e13);
                u32 w0, w1, w2, w3;
                plswap(ue, uo, w0, w2);
                plswap(ve, vo, w1, w3);
                union { bf16x8 v; u32 w[4]; } pu;
                pu.w[0] = w0; pu.w[1] = w1; pu.w[2] = w2; pu.w[3] = w3;
                pa[2 * kt + gp] = pu.v;
            }
        lsum += sq;

        // single end-of-iter barrier: K(t+1)/V(t+1) (issued at top, ~full body ago) must land
        if (t < 31) {
            asm volatile("s_waitcnt vmcnt(0)" ::: "memory");
            __builtin_amdgcn_s_barrier();
            asm volatile("" ::: "memory");
        }
        vw = (vw == 2) ? 0 : vw + 1;
        vr = (vr == 2) ? 0 : vr + 1;
    }

    // drain: PV(31) reads Vl[31%3 = 1] (staged at t=30, drained at t=30's barrier)
#pragma unroll
    for (int s = 0; s < 4; ++s) {
        bf16x8 bv0 = frag8(Vl[1], l31,      2 * s + h);
        bf16x8 bv1 = frag8(Vl[1], 32 + l31, 2 * s + h);
        oacc[0] = mfma32(pa[s], bv0, oacc[0]);
        oacc[1] = mfma32(pa[s], bv1, oacc[1]);
    }

    // 1/l: combine h-halves in-register; redistribute to C-row layout via shuffles (no LDS)
    float linv_own;
    {
        float l2 = lsum + __shfl_xor(lsum, 32);   // lane q (both halves) holds l for query q
        linv_own = 1.0f / l2;
    }
    int b_ = bh >> 4, hh = bh & 15;
    for (int g = 0; g < 4; ++g) {
#pragma unroll
        for (int r = 0; r < 4; ++r) {
            float iv = __shfl(linv_own, 8 * g + 4 * h + r);
            int row = b_ * 2048 + m0 + wave * 32 + 8 * g + 4 * h + r;
            for (int dt = 0; dt < 2; ++dt)
                A2[row * 1024 + hh * 64 + dt * 32 + l31] = f2bf(oacc[dt][g * 4 + r] * iv);
        }
    }
}

// ---------------- output projection GEMM: 256x128 tiles, 8 waves @ 64x64/wave, depth-2 vmcnt ----------------
// 256 blocks of 512 threads. LDS 96 KB -> 1 block/CU; exactly one dispatch round.
__global__ __launch_bounds__(512, 2) void k_gemm_out(const u16* __restrict__ A, const u16* __restrict__ BT,
                                                     const float* __restrict__ bo, float* __restrict__ out) {
    __shared__ u16 Al[2][256 * 64];
    __shared__ u16 Bl[2][128 * 64];
    int tid = threadIdx.x;
    int wave = tid >> 6, lane = tid & 63, l31 = lane & 31, h2 = lane >> 5;
    int wr = wave >> 1, wc = wave & 1;

    // bijective XCD swizzle: 256 = 8 * 32
    int b = blockIdx.x;
    int wg = (b & 7) * 32 + (b >> 3);
    int row0 = (wg >> 3) * 256, col0 = (wg & 7) * 128;

    const u16* Am = A  + (size_t)row0 * 1024;
    const u16* Bm = BT + (size_t)col0 * 1024;

    f32x16 acc[2][2] = {};

    int srA[4], sgsA[4], sdstA[4];
#pragma unroll
    for (int l = 0; l < 4; ++l) {
        int idx = tid + l * 512;
        srA[l] = idx >> 3; sgsA[l] = ((idx & 7) ^ (srA[l] & 7)) * 8; sdstA[l] = idx * 8;
    }
    int srB[2], sgsB[2], sdstB[2];
#pragma unroll
    for (int l = 0; l < 2; ++l) {
        int idx = tid + l * 512;
        srB[l] = idx >> 3; sgsB[l] = ((idx & 7) ^ (srB[l] & 7)) * 8; sdstB[l] = idx * 8;
    }

#define OUT_STAGE(bufi, k0) \
    { _Pragma("unroll") for (int l = 0; l < 4; ++l) \
        g2l16(&Al[bufi][sdstA[l]], Am + srA[l] * 1024 + (k0) + sgsA[l]); \
      _Pragma("unroll") for (int l = 0; l < 2; ++l) \
        g2l16(&Bl[bufi][sdstB[l]], Bm + srB[l] * 1024 + (k0) + sgsB[l]); }

#define OUT_COMPUTE(bufi) \
    { _Pragma("unroll") for (int kk = 0; kk < 4; ++kk) { \
        bf16x8 a0_ = frag8(Al[bufi], wr * 64 + l31,      2 * kk + h2); \
        bf16x8 a1_ = frag8(Al[bufi], wr * 64 + 32 + l31, 2 * kk + h2); \
        bf16x8 b0_ = frag8(Bl[bufi], wc * 64 + l31,      2 * kk + h2); \
        bf16x8 b1_ = frag8(Bl[bufi], wc * 64 + 32 + l31, 2 * kk + h2); \
        acc[0][0] = mfma32(a0_, b0_, acc[0][0]); \
        acc[0][1] = mfma32(a0_, b1_, acc[0][1]); \
        acc[1][0] = mfma32(a1_, b0_, acc[1][0]); \
        acc[1][1] = mfma32(a1_, b1_, acc[1][1]); } }

    OUT_STAGE(0, 0)
    OUT_STAGE(1, 64)

    for (int t = 0; t < 15; ++t) {
        int cur = t & 1;
        asm volatile("s_waitcnt vmcnt(6)" ::: "memory");
        __builtin_amdgcn_s_barrier();
        asm volatile("" ::: "memory");
        __builtin_amdgcn_s_setprio(1);
        OUT_COMPUTE(cur)
        __builtin_amdgcn_s_setprio(0);
        asm volatile("" ::: "memory");
        __builtin_amdgcn_s_barrier();
        if (t < 14) OUT_STAGE(cur, (t + 2) * 64)
    }
    asm volatile("s_waitcnt vmcnt(0)" ::: "memory");
    __builtin_amdgcn_s_barrier();
    asm volatile("" ::: "memory");
    OUT_COMPUTE(1)
#undef OUT_STAGE
#undef OUT_COMPUTE

#pragma unroll
    for (int ni = 0; ni < 2; ++ni) {
        int c = col0 + wc * 64 + ni * 32 + l31;
        float bias = bo[c];
#pragma unroll
        for (int mi = 0; mi < 2; ++mi)
#pragma unroll
            for (int reg = 0; reg < 16; ++reg) {
                int rowg = row0 + wr * 64 + mi * 32 + (reg & 3) + 8 * (reg >> 2) + 4 * h2;
                out[(size_t)rowg * 1024 + c] = acc[mi][ni][reg] + bias;
            }
    }
}

extern "C" void kernel_launch(void* const* d_in, const int* in_sizes, int n_in,
                              void* d_out, int out_size, void* d_ws, size_t ws_size,
                              hipStream_t stream) {
    const float* x  = (const float*)d_in[0];
    const float* Wq = (const float*)d_in[1];
    const float* bq = (const float*)d_in[2];
    const float* Wk = (const float*)d_in[3];
    const float* bk = (const float*)d_in[4];
    const float* Wv = (const float*)d_in[5];
    const float* bv = (const float*)d_in[6];
    const float* Wo = (const float*)d_in[7];
    const float* bo = (const float*)d_in[8];
    float* out = (float*)d_out;

    // Workspace layout (peak 72 MB). A2 aliases xb: xb is dead after k_gemm_qkv,
    // and A2 is first written by k_attn which runs strictly later on this stream.
    char* ws = (char*)d_ws;
    u16* xb    = (u16*)ws; ws += (size_t)ROWS * DM * 2;        // 16 MB
    u16* WqkvT = (u16*)ws; ws += (size_t)NQKV * DM * 2;        // 6 MB
    u16* WoT   = (u16*)ws; ws += (size_t)DM * DM * 2;          // 2 MB
    u16* Qb    = (u16*)ws; ws += (size_t)BH * SEQ * DEPTH * 2; // 16 MB
    u16* Kb    = (u16*)ws; ws += (size_t)BH * SEQ * DEPTH * 2; // 16 MB
    u16* VTb   = (u16*)ws; ws += (size_t)BH * SEQ * DEPTH * 2; // 16 MB
    u16* A2    = xb;                                           // aliased (16 MB)
    (void)ws_size;

    k_prep     <<<dim3(3072),   dim3(256), 0, stream>>>(x, Wq, Wk, Wv, Wo, xb, WqkvT, WoT);
    k_gemm_qkv <<<dim3(768),    dim3(512), 0, stream>>>(xb, WqkvT, bq, bk, bv, Qb, Kb, VTb);
    k_attn     <<<dim3(1024),   dim3(256), 0, stream>>>(Qb, Kb, VTb, A2);
    k_gemm_out <<<dim3(256),    dim3(512), 0, stream>>>(A2, WoT, bo, out);
}